// Round 17
// baseline (203.154 us; speedup 1.0000x reference)
//
#include <hip/hip_runtime.h>
#include <hip/hip_bf16.h>
#include <math.h>

typedef __attribute__((ext_vector_type(8))) short short8;
typedef __attribute__((ext_vector_type(4))) float f32x4;
typedef __attribute__((ext_vector_type(2))) float f32x2;
typedef __attribute__((ext_vector_type(4))) unsigned int u32x4;

// ---- packed fp32 (VOP3P) helpers ----
__device__ __forceinline__ f32x2 pk_add(f32x2 a, f32x2 b) {
  f32x2 d; asm("v_pk_add_f32 %0, %1, %2" : "=v"(d) : "v"(a), "v"(b)); return d;
}
__device__ __forceinline__ f32x2 pk_fma(f32x2 a, f32x2 b, f32x2 c) {
  f32x2 d; asm("v_pk_fma_f32 %0, %1, %2, %3" : "=v"(d) : "v"(a), "v"(b), "v"(c)); return d;
}
__device__ __forceinline__ f32x2 pk_abs(f32x2 a) {
  union { f32x2 f; unsigned int u[2]; } x; x.f = a;
  x.u[0] &= 0x7fffffffu; x.u[1] &= 0x7fffffffu;
  return x.f;
}
__device__ __forceinline__ f32x2 unpk(unsigned int w) {
  union { f32x2 f; unsigned int u[2]; } x;
  x.u[0] = w << 16;
  x.u[1] = w & 0xffff0000u;
  return x.f;
}

// DPP partial-sum (VALU pipe)
template <int CTRL>
__device__ __forceinline__ float dpp_add(float x) {
  int y = __builtin_amdgcn_update_dpp(0, __builtin_bit_cast(int, x), CTRL, 0xF, 0xF, true);
  return x + __builtin_bit_cast(float, y);
}
__device__ __forceinline__ float row16_sum(float p) {
  p = dpp_add<0xB1>(p);
  p = dpp_add<0x4E>(p);
  p = dpp_add<0x124>(p);
  p = dpp_add<0x128>(p);
  return p;
}

__device__ __forceinline__ void load_lds16(const void* g, void* l) {
  __builtin_amdgcn_global_load_lds(
      (const __attribute__((address_space(1))) unsigned int*)g,
      (__attribute__((address_space(3))) unsigned int*)l, 16, 0, 0);
}

// ---------------- bf16 MFMA GEMM, BK=64 (half the barriers), XCD-swizzled ----------------
__global__ __launch_bounds__(256) void gemm_mfma(
    const __hip_bfloat16* __restrict__ A, const __hip_bfloat16* __restrict__ B,
    const float* __restrict__ bl, const float* __restrict__ br, int halfN,
    __hip_bfloat16* __restrict__ out, int M, int K, int Nout) {
  __shared__ __hip_bfloat16 As[128 * 64];
  __shared__ __hip_bfloat16 Bs[128 * 64];
  // bijective chunked XCD swizzle (m204)
  int gx = gridDim.x;
  int nwg = gx * gridDim.y;
  int lid = blockIdx.y * gx + blockIdx.x;
  int q = nwg >> 3, r = nwg & 7;
  int xcd = lid & 7, li = lid >> 3;
  int wgid = (xcd < r ? xcd * (q + 1) : r * (q + 1) + (xcd - r) * q) + li;
  int bx = wgid % gx, by = wgid / gx;

  int t = threadIdx.x;
  int w = t >> 6, l = t & 63;
  int lr = l & 15, lh = l >> 4;
  int wr = w >> 1, wc = w & 1;
  int m0 = by * 128, n0 = bx * 128;
  f32x4 acc[4][4] = {};
  int nk = K >> 6;   // BK = 64
  for (int ks = 0; ks < nk; ++ks) {
    int k0 = ks << 6;
    // stage A-tile 128x64 (16KB = 1024 x 16B chunks, 4 per thread)
#pragma unroll
    for (int p = 0; p < 4; ++p) {
      int c = p * 256 + t;
      int row = c >> 3, sub = c & 7;
      int gm = m0 + row; if (gm >= M) gm = M - 1;
      const __hip_bfloat16* gsrc = A + (size_t)gm * K + k0 + sub * 8;
      char* ldst = (char*)As + (size_t)c * 16;
      load_lds16(gsrc, ldst);
    }
#pragma unroll
    for (int p = 0; p < 4; ++p) {
      int c = p * 256 + t;
      int row = c >> 3, sub = c & 7;
      const __hip_bfloat16* gsrc = B + (size_t)(n0 + row) * K + k0 + sub * 8;
      char* ldst = (char*)Bs + (size_t)c * 16;
      load_lds16(gsrc, ldst);
    }
    __syncthreads();
#pragma unroll
    for (int kk = 0; kk < 2; ++kk) {
      short8 af[4], bf[4];
#pragma unroll
      for (int mt = 0; mt < 4; ++mt)
        af[mt] = *(const short8*)(As + (size_t)(wr * 64 + mt * 16 + lr) * 64 + kk * 32 + lh * 8);
#pragma unroll
      for (int nt = 0; nt < 4; ++nt)
        bf[nt] = *(const short8*)(Bs + (size_t)(wc * 64 + nt * 16 + lr) * 64 + kk * 32 + lh * 8);
#pragma unroll
      for (int mt = 0; mt < 4; ++mt)
#pragma unroll
        for (int nt = 0; nt < 4; ++nt)
          acc[mt][nt] = __builtin_amdgcn_mfma_f32_16x16x32_bf16(af[mt], bf[nt], acc[mt][nt], 0, 0, 0);
    }
    __syncthreads();
  }
#pragma unroll
  for (int mt = 0; mt < 4; ++mt) {
#pragma unroll
    for (int r2 = 0; r2 < 4; ++r2) {
      int gm = m0 + wr * 64 + mt * 16 + lh * 4 + r2;
      if (gm >= M) continue;
#pragma unroll
      for (int nt = 0; nt < 4; ++nt) {
        int gn = n0 + wc * 64 + nt * 16 + lr;
        float bv = (gn < halfN) ? bl[gn] : br[gn - halfN];
        out[(size_t)gm * Nout + gn] = __float2bfloat16(acc[mt][nt][r2] + bv);
      }
    }
  }
}

// ---------------- fused prep: vectorized casts (short8 stores) + degree histogram ----------------
struct CastSeg { const float* src; __hip_bfloat16* dst; int rows, K, Kp, row0, start; };
struct CastArgs { CastSeg s[7]; int total; };  // start/total in 8-elem GROUPS

__global__ __launch_bounds__(256) void k_prep(CastArgs A, const int* __restrict__ ei,
                                              int E, int N, int* __restrict__ deg) {
  int stride = gridDim.x * blockDim.x;
  int tid0 = blockIdx.x * blockDim.x + threadIdx.x;
  for (int gidx = tid0; gidx < A.total; gidx += stride) {
    int si = 0;
#pragma unroll
    for (int j = 1; j < 7; j++) if (gidx >= A.s[j].start) si = j;
    CastSeg sg = A.s[si];
    int lg = gidx - sg.start;           // group within segment
    int gpr = sg.Kp >> 3;               // groups per row (Kp % 8 == 0 always)
    int r = lg / gpr, k0 = (lg - r * gpr) << 3;
    const float* srow = sg.src + (size_t)r * sg.K;
    short8 o;
#pragma unroll
    for (int j = 0; j < 8; ++j) {
      int k = k0 + j;
      float v = (k < sg.K) ? srow[k] : 0.f;
      __hip_bfloat16 b = __float2bfloat16(v);
      o[j] = __builtin_bit_cast(short, b);
    }
    *(short8*)(sg.dst + (size_t)(sg.row0 + r) * sg.Kp + k0) = o;
  }
  int ET = E + N;
  for (int e = tid0; e < ET; e += stride) {
    int d = (e < E) ? ei[E + e] : (e - E);
    atomicAdd(&deg[d], 1);
  }
}

// ---------------- scan + degree-bucket permutation (single block) ----------------
__global__ __launch_bounds__(256) void k_scan_perm(const int* __restrict__ deg, int N,
                                                   int* __restrict__ rp, int* __restrict__ cursor,
                                                   int* __restrict__ perm) {
  __shared__ int part[256];
  __shared__ int bcnt[64];
  __shared__ int boff[64];
  int t = threadIdx.x;
  int chunk = (N + 255) / 256;
  int lo = t * chunk;
  int hi = lo + chunk; if (hi > N) hi = N;
  int s = 0;
  for (int i = lo; i < hi; ++i) s += deg[i];
  part[t] = s;
  if (t < 64) bcnt[t] = 0;
  __syncthreads();
  for (int off = 1; off < 256; off <<= 1) {
    int x = (t >= off) ? part[t - off] : 0;
    __syncthreads();
    part[t] += x;
    __syncthreads();
  }
  int run = (t == 0) ? 0 : part[t - 1];
  for (int i = lo; i < hi; ++i) {
    rp[i] = run;
    cursor[i] = run;
    run += deg[i];
    int b = deg[i] < 63 ? deg[i] : 63;
    atomicAdd(&bcnt[b], 1);
  }
  if (t == 255) rp[N] = run;
  __syncthreads();
  if (t == 0) {
    int acc = 0;
    for (int b = 63; b >= 0; --b) { boff[b] = acc; acc += bcnt[b]; }  // descending degree
  }
  __syncthreads();
  for (int i = lo; i < hi; ++i) {
    int b = deg[i] < 63 ? deg[i] : 63;
    int pos = atomicAdd(&boff[b], 1);
    perm[pos] = i;
  }
}

// scatter + zero the srcs pad (unconditional prefetch reads land in valid memory)
__global__ void k_scatter(const int* __restrict__ ei, int E, int N,
                          int* __restrict__ cursor, int* __restrict__ srcs) {
  int e = blockIdx.x * blockDim.x + threadIdx.x;
  int ET = E + N;
  if (e >= ET) {
    if (e < ET + 64) srcs[e] = 0;
    return;
  }
  int s = (e < E) ? ei[e] : (e - E);
  int d = (e < E) ? ei[E + e] : (e - E);
  int pos = atomicAdd(&cursor[d], 1);
  srcs[pos] = s;
}

// ---------------- layers 1-2 edge phase: 2 edges/wave, 2-deep prefetch ----------------
__global__ __launch_bounds__(256) void k_edge2(
    const __hip_bfloat16* __restrict__ xl, const __hip_bfloat16* __restrict__ xr,
    const int* __restrict__ rp, const int* __restrict__ srcs,
    const int* __restrict__ perm, const float* __restrict__ att,
    const float* __restrict__ bias, int N, __hip_bfloat16* __restrict__ out) {
  const int LD = 1024;
  int lane = threadIdx.x & 63;
  int hl = lane & 31;
  bool hi = lane >= 32;
  int nw = (blockIdx.x * blockDim.x + threadIdx.x) >> 6;
  if (nw >= N) return;
  int n = __builtin_amdgcn_readfirstlane(perm[nw]);

  f32x2 a06[8], a04[8], xrv2[8];
#pragma unroll
  for (int p = 0; p < 8; ++p) {
    float alo = att[hl * 16 + 2 * p], ahi = att[hl * 16 + 2 * p + 1];
    a06[p].x = 0.6f * alo; a06[p].y = 0.6f * ahi;
    a04[p].x = 0.4f * alo; a04[p].y = 0.4f * ahi;
  }
  {
    const unsigned int* xw = (const unsigned int*)(xr + (size_t)n * LD + hl * 16);
#pragma unroll
    for (int p = 0; p < 8; ++p) xrv2[p] = unpk(xw[p]);
  }

  int s0 = __builtin_amdgcn_readfirstlane(rp[n]);
  int s1 = __builtin_amdgcn_readfirstlane(rp[n + 1]);
  int len = s1 - s0;
  int lenA = (len + 1) >> 1;
  int lenB = len - lenA;
  int iA = s0, iB = s0 + lenA;
  unsigned laneOff = (unsigned)(hl * 32);

  float sum = 0.f;
  f32x2 acc2[8];
#pragma unroll
  for (int p = 0; p < 8; ++p) { acc2[p].x = 0.f; acc2[p].y = 0.f; }

  auto loadPair = [&](int t, u32x4& lo, u32x4& hh) {
    unsigned offA = ((unsigned)srcs[iA + t]) << 11;   // *2048 B/row
    unsigned offB = ((unsigned)srcs[iB + t]) << 11;
    unsigned off = (hi ? offB : offA) + laneOff;
    const u32x4* p = (const u32x4*)((const char*)xl + off);
    lo = p[0]; hh = p[1];
  };

  u32x4 lo0, hi0, lo1, hi1, lo2, hi2;
  loadPair(0, lo0, hi0);
  loadPair(1, lo1, hi1);
  for (int t = 0; t < lenA; ++t) {
    loadPair(t + 2, lo2, hi2);
    f32x2 xv2[8], p2; p2.x = 0.f; p2.y = 0.f;
#pragma unroll
    for (int p = 0; p < 8; ++p) {
      unsigned int wv = (p < 4) ? lo0[p & 3] : hi0[p & 3];
      xv2[p] = unpk(wv);
      f32x2 s = pk_add(xv2[p], xrv2[p]);
      f32x2 sa = pk_abs(s);
      p2 = pk_fma(a06[p], s, p2);
      p2 = pk_fma(a04[p], sa, p2);
    }
    float pp = p2.x + p2.y;
    pp = dpp_add<0xB1>(pp);
    pp = dpp_add<0x4E>(pp);
    pp += __shfl_xor(pp, 4, 64);
    float wgt = __expf(pp);
    if (hi && t >= lenB) wgt = 0.f;
    sum += wgt;
    f32x2 w2; w2.x = wgt; w2.y = wgt;
#pragma unroll
    for (int p = 0; p < 8; ++p) acc2[p] = pk_fma(w2, xv2[p], acc2[p]);
    lo0 = lo1; hi0 = hi1; lo1 = lo2; hi1 = hi2;
  }

  sum += __shfl_xor(sum, 32, 64);
#pragma unroll
  for (int p = 0; p < 8; ++p) {
    f32x2 o;
    o.x = __shfl_xor(acc2[p].x, 32, 64);
    o.y = __shfl_xor(acc2[p].y, 32, 64);
    acc2[p] = pk_add(acc2[p], o);
  }
  float inv = 1.f / (sum + 1e-16f);
  int cbase = hl * 16 + (hi ? 8 : 0);
  short8 o;
#pragma unroll
  for (int q = 0; q < 4; ++q) {
    f32x2 v = hi ? acc2[4 + q] : acc2[q];
    float r0 = v.x * inv + bias[cbase + 2 * q];
    float r1 = v.y * inv + bias[cbase + 2 * q + 1];
    r0 = r0 > 0.f ? r0 : expm1f(r0);   // ELU
    r1 = r1 > 0.f ? r1 : expm1f(r1);
    __hip_bfloat16 b0 = __float2bfloat16(r0);
    __hip_bfloat16 b1 = __float2bfloat16(r1);
    o[2 * q] = __builtin_bit_cast(short, b0);
    o[2 * q + 1] = __builtin_bit_cast(short, b1);
  }
  *(short8*)(out + (size_t)n * 512 + cbase) = o;
}

// ---------------- layer 3 edge phase: 4 edges per wave ----------------
__global__ __launch_bounds__(256) void k_edge4(
    const __hip_bfloat16* __restrict__ xl, const __hip_bfloat16* __restrict__ xr,
    const int* __restrict__ rp, const int* __restrict__ srcs,
    const int* __restrict__ perm, const float* __restrict__ att,
    const float* __restrict__ bias, int N, float* __restrict__ out) {
  const int LD = 256;
  int lane = threadIdx.x & 63;
  int hl = lane & 15;
  int g = lane >> 4;
  int nw = (blockIdx.x * blockDim.x + threadIdx.x) >> 6;
  if (nw >= N) return;
  int n = __builtin_amdgcn_readfirstlane(perm[nw]);

  f32x2 a06[4], a04[4], xrv2[4];
#pragma unroll
  for (int p = 0; p < 4; ++p) {
    float alo = att[hl * 8 + 2 * p], ahi = att[hl * 8 + 2 * p + 1];
    a06[p].x = 0.6f * alo; a06[p].y = 0.6f * ahi;
    a04[p].x = 0.4f * alo; a04[p].y = 0.4f * ahi;
  }
  {
    const unsigned int* xw = (const unsigned int*)(xr + (size_t)n * LD + hl * 8);
#pragma unroll
    for (int p = 0; p < 4; ++p) xrv2[p] = unpk(xw[p]);
  }

  int s0 = __builtin_amdgcn_readfirstlane(rp[n]);
  int s1 = __builtin_amdgcn_readfirstlane(rp[n + 1]);
  int len = s1 - s0;
  int base = len >> 2, rem = len & 3;
  int l0 = base + (rem > 0 ? 1 : 0);
  int l1 = base + (rem > 1 ? 1 : 0);
  int l2 = base + (rem > 2 ? 1 : 0);
  int st0 = 0, st1 = l0, st2 = l0 + l1, st3 = l0 + l1 + l2;
  int lg = base + ((g < rem) ? 1 : 0);
  int itmax = (len < 4) ? 1 : l0;
  if (l0 == 0) itmax = 0;
  unsigned laneOff = (unsigned)(hl * 16);

  float sum = 0.f;
  f32x2 acc2[4];
#pragma unroll
  for (int p = 0; p < 4; ++p) { acc2[p].x = 0.f; acc2[p].y = 0.f; }

  auto loadRow = [&](int t) -> u32x4 {
    unsigned o0 = ((unsigned)srcs[s0 + st0 + t]) << 9;
    unsigned o1 = ((unsigned)srcs[s0 + st1 + t]) << 9;
    unsigned o2 = ((unsigned)srcs[s0 + st2 + t]) << 9;
    unsigned o3 = ((unsigned)srcs[s0 + st3 + t]) << 9;
    unsigned off = ((g == 0) ? o0 : (g == 1) ? o1 : (g == 2) ? o2 : o3) + laneOff;
    return *(const u32x4*)((const char*)xl + off);
  };

  u32x4 cur = loadRow(0);
  for (int t = 0; t < itmax; ++t) {
    u32x4 nxt = loadRow(t + 1);
    f32x2 xv2[4], p2; p2.x = 0.f; p2.y = 0.f;
#pragma unroll
    for (int p = 0; p < 4; ++p) {
      xv2[p] = unpk(cur[p]);
      f32x2 s = pk_add(xv2[p], xrv2[p]);
      f32x2 sa = pk_abs(s);
      p2 = pk_fma(a06[p], s, p2);
      p2 = pk_fma(a04[p], sa, p2);
    }
    float pp = p2.x + p2.y;
    pp = row16_sum(pp);
    float wgt = (t < lg) ? __expf(pp) : 0.f;
    sum += wgt;
    f32x2 w2; w2.x = wgt; w2.y = wgt;
#pragma unroll
    for (int p = 0; p < 4; ++p) acc2[p] = pk_fma(w2, xv2[p], acc2[p]);
    cur = nxt;
  }

  sum += __shfl_xor(sum, 16, 64);
  sum += __shfl_xor(sum, 32, 64);
#pragma unroll
  for (int p = 0; p < 4; ++p) {
    acc2[p].x += __shfl_xor(acc2[p].x, 16, 64);
    acc2[p].y += __shfl_xor(acc2[p].y, 16, 64);
    acc2[p].x += __shfl_xor(acc2[p].x, 32, 64);
    acc2[p].y += __shfl_xor(acc2[p].y, 32, 64);
  }
  float inv = 1.f / (sum + 1e-16f);
  f32x2 v = (g == 0) ? acc2[0] : (g == 1) ? acc2[1] : (g == 2) ? acc2[2] : acc2[3];
  int cb = hl * 8 + 2 * g;
  f32x2 r;
  r.x = v.x * inv + bias[cb];
  r.y = v.y * inv + bias[cb + 1];
  *(f32x2*)(out + (size_t)n * 128 + cb) = r;
}

extern "C" void kernel_launch(void* const* d_in, const int* in_sizes, int n_in,
                              void* d_out, int out_size, void* d_ws, size_t ws_size,
                              hipStream_t stream) {
  const int IN = 77, Kp1 = 128, Hh = 4, Cc = 128, HC = Hh * Cc;  // Kp1 padded to 128 for BK=64
  const int N = in_sizes[0] / IN;
  const int E = in_sizes[1] / 2;
  const int ET = E + N;

  const float* x   = (const float*)d_in[0];
  const int*   ei  = (const int*)d_in[1];
  const float* Wl1 = (const float*)d_in[2];  const float* bl1 = (const float*)d_in[3];
  const float* Wr1 = (const float*)d_in[4];  const float* br1 = (const float*)d_in[5];
  const float* att1= (const float*)d_in[6];  const float* b1  = (const float*)d_in[7];
  const float* Wl2 = (const float*)d_in[8];  const float* bl2 = (const float*)d_in[9];
  const float* Wr2 = (const float*)d_in[10]; const float* br2 = (const float*)d_in[11];
  const float* att2= (const float*)d_in[12]; const float* b2  = (const float*)d_in[13];
  const float* Wl3 = (const float*)d_in[14]; const float* bl3 = (const float*)d_in[15];
  const float* Wr3 = (const float*)d_in[16]; const float* br3 = (const float*)d_in[17];
  const float* att3= (const float*)d_in[18]; const float* b3  = (const float*)d_in[19];
  float* out = (float*)d_out;

  char* w = (char*)d_ws;
  size_t off = 0;
  auto alloc = [&](size_t bytes) -> void* {
    void* p = w + off;
    off += (bytes + 255) & ~(size_t)255;
    return p;
  };
  __hip_bfloat16* xlr = (__hip_bfloat16*)alloc((size_t)N * 2 * HC * 2);
  __hip_bfloat16* hb  = (__hip_bfloat16*)alloc((size_t)N * HC * 2);
  __hip_bfloat16* Wc1 = (__hip_bfloat16*)alloc((size_t)2 * HC * Kp1 * 2);
  __hip_bfloat16* Wc2 = (__hip_bfloat16*)alloc((size_t)2 * HC * HC * 2);
  __hip_bfloat16* Wc3 = (__hip_bfloat16*)alloc((size_t)2 * Cc * HC * 2);
  int*   deg    = (int*)alloc((size_t)N * 4);
  int*   rp     = (int*)alloc((size_t)(N + 1) * 4);
  int*   cursor = (int*)alloc((size_t)N * 4);
  int*   srcs   = (int*)alloc((size_t)(ET + 64) * 4);
  int*   perm   = (int*)alloc((size_t)N * 4);

  // ---- fused prep: vectorized casts (group = 8 elems) + degree histogram ----
  CastArgs CA;
  int cum = 0;
  auto seg = [&](int idx, const float* src, __hip_bfloat16* dst, int rows, int K, int Kp, int row0) {
    CA.s[idx] = {src, dst, rows, K, Kp, row0, cum};
    cum += rows * (Kp >> 3);   // groups
  };
  seg(0, Wl1, Wc1, HC, IN, Kp1, 0);
  seg(1, Wr1, Wc1, HC, IN, Kp1, HC);
  seg(2, Wl2, Wc2, HC, HC, HC, 0);
  seg(3, Wr2, Wc2, HC, HC, HC, HC);
  seg(4, Wl3, Wc3, Cc, HC, HC, 0);
  seg(5, Wr3, Wc3, Cc, HC, HC, Cc);
  seg(6, x,   hb,  N,  IN, Kp1, 0);
  CA.total = cum;

  hipMemsetAsync(deg, 0, (size_t)N * 4, stream);
  k_prep<<<1024, 256, 0, stream>>>(CA, ei, E, N, deg);
  k_scan_perm<<<1, 256, 0, stream>>>(deg, N, rp, cursor, perm);
  k_scatter<<<(ET + 64 + 255) / 256, 256, 0, stream>>>(ei, E, N, cursor, srcs);

  int nodeBlocks = (N + 3) / 4;
  int mb = (N + 127) / 128;

  // ---- layer 1 (K = 128 padded) ----
  {
    dim3 g(2 * HC / 128, mb);
    gemm_mfma<<<g, 256, 0, stream>>>(hb, Wc1, bl1, br1, HC, xlr, N, Kp1, 2 * HC);
    k_edge2<<<nodeBlocks, 256, 0, stream>>>(xlr, xlr + HC, rp, srcs, perm, att1, b1, N, hb);
  }
  // ---- layer 2 ----
  {
    dim3 g(2 * HC / 128, mb);
    gemm_mfma<<<g, 256, 0, stream>>>(hb, Wc2, bl2, br2, HC, xlr, N, HC, 2 * HC);
    k_edge2<<<nodeBlocks, 256, 0, stream>>>(xlr, xlr + HC, rp, srcs, perm, att2, b2, N, hb);
  }
  // ---- layer 3 (1 head, 128 ch, fp32 out, no ELU) ----
  {
    dim3 g(2 * Cc / 128, mb);
    gemm_mfma<<<g, 256, 0, stream>>>(hb, Wc3, bl3, br3, Cc, xlr, N, HC, 2 * Cc);
    k_edge4<<<nodeBlocks, 256, 0, stream>>>(xlr, xlr + Cc, rp, srcs, perm, att3, b3, N, out);
  }
}

// Round 18
// 190.242 us; speedup vs baseline: 1.0679x; 1.0679x over previous
//
#include <hip/hip_runtime.h>
#include <hip/hip_bf16.h>
#include <math.h>

typedef __attribute__((ext_vector_type(8))) short short8;
typedef __attribute__((ext_vector_type(4))) float f32x4;
typedef __attribute__((ext_vector_type(2))) float f32x2;
typedef __attribute__((ext_vector_type(4))) unsigned int u32x4;

// ---- packed fp32 (VOP3P) helpers ----
__device__ __forceinline__ f32x2 pk_add(f32x2 a, f32x2 b) {
  f32x2 d; asm("v_pk_add_f32 %0, %1, %2" : "=v"(d) : "v"(a), "v"(b)); return d;
}
__device__ __forceinline__ f32x2 pk_fma(f32x2 a, f32x2 b, f32x2 c) {
  f32x2 d; asm("v_pk_fma_f32 %0, %1, %2, %3" : "=v"(d) : "v"(a), "v"(b), "v"(c)); return d;
}
__device__ __forceinline__ f32x2 pk_abs(f32x2 a) {
  union { f32x2 f; unsigned int u[2]; } x; x.f = a;
  x.u[0] &= 0x7fffffffu; x.u[1] &= 0x7fffffffu;
  return x.f;
}
__device__ __forceinline__ f32x2 unpk(unsigned int w) {
  union { f32x2 f; unsigned int u[2]; } x;
  x.u[0] = w << 16;
  x.u[1] = w & 0xffff0000u;
  return x.f;
}

// DPP partial-sum (VALU pipe)
template <int CTRL>
__device__ __forceinline__ float dpp_add(float x) {
  int y = __builtin_amdgcn_update_dpp(0, __builtin_bit_cast(int, x), CTRL, 0xF, 0xF, true);
  return x + __builtin_bit_cast(float, y);
}
__device__ __forceinline__ float row16_sum(float p) {
  p = dpp_add<0xB1>(p);
  p = dpp_add<0x4E>(p);
  p = dpp_add<0x124>(p);
  p = dpp_add<0x128>(p);
  return p;
}

__device__ __forceinline__ void load_lds16(const void* g, void* l) {
  __builtin_amdgcn_global_load_lds(
      (const __attribute__((address_space(1))) unsigned int*)g,
      (__attribute__((address_space(3))) unsigned int*)l, 16, 0, 0);
}

// ---------------- bf16 MFMA GEMM, BK=32 (R16 geometry), XCD-swizzled ----------------
__global__ __launch_bounds__(256) void gemm_mfma(
    const __hip_bfloat16* __restrict__ A, const __hip_bfloat16* __restrict__ B,
    const float* __restrict__ bl, const float* __restrict__ br, int halfN,
    __hip_bfloat16* __restrict__ out, int M, int K, int Nout) {
  __shared__ __hip_bfloat16 As[128 * 32];
  __shared__ __hip_bfloat16 Bs[128 * 32];
  // bijective chunked XCD swizzle (m204)
  int gx = gridDim.x;
  int nwg = gx * gridDim.y;
  int lid = blockIdx.y * gx + blockIdx.x;
  int q = nwg >> 3, r = nwg & 7;
  int xcd = lid & 7, li = lid >> 3;
  int wgid = (xcd < r ? xcd * (q + 1) : r * (q + 1) + (xcd - r) * q) + li;
  int bx = wgid % gx, by = wgid / gx;

  int t = threadIdx.x;
  int w = t >> 6, l = t & 63;
  int lr = l & 15, lh = l >> 4;
  int wr = w >> 1, wc = w & 1;
  int m0 = by * 128, n0 = bx * 128;
  f32x4 acc[4][4] = {};
  int nk = K >> 5;
  for (int ks = 0; ks < nk; ++ks) {
    int k0 = ks << 5;
#pragma unroll
    for (int p = 0; p < 2; ++p) {
      int c = p * 256 + t;
      int row = c >> 2, sub = c & 3;
      int gm = m0 + row; if (gm >= M) gm = M - 1;
      const __hip_bfloat16* gsrc = A + (size_t)gm * K + k0 + sub * 8;
      char* ldst = (char*)As + (size_t)(p * 256 + w * 64) * 16;
      load_lds16(gsrc, ldst);
    }
#pragma unroll
    for (int p = 0; p < 2; ++p) {
      int c = p * 256 + t;
      int row = c >> 2, sub = c & 3;
      const __hip_bfloat16* gsrc = B + (size_t)(n0 + row) * K + k0 + sub * 8;
      char* ldst = (char*)Bs + (size_t)(p * 256 + w * 64) * 16;
      load_lds16(gsrc, ldst);
    }
    __syncthreads();
    short8 af[4], bf[4];
#pragma unroll
    for (int mt = 0; mt < 4; ++mt)
      af[mt] = *(const short8*)(As + (size_t)(wr * 64 + mt * 16 + lr) * 32 + lh * 8);
#pragma unroll
    for (int nt = 0; nt < 4; ++nt)
      bf[nt] = *(const short8*)(Bs + (size_t)(wc * 64 + nt * 16 + lr) * 32 + lh * 8);
#pragma unroll
    for (int mt = 0; mt < 4; ++mt)
#pragma unroll
      for (int nt = 0; nt < 4; ++nt)
        acc[mt][nt] = __builtin_amdgcn_mfma_f32_16x16x32_bf16(af[mt], bf[nt], acc[mt][nt], 0, 0, 0);
    __syncthreads();
  }
#pragma unroll
  for (int mt = 0; mt < 4; ++mt) {
#pragma unroll
    for (int r2 = 0; r2 < 4; ++r2) {
      int gm = m0 + wr * 64 + mt * 16 + lh * 4 + r2;
      if (gm >= M) continue;
#pragma unroll
      for (int nt = 0; nt < 4; ++nt) {
        int gn = n0 + wc * 64 + nt * 16 + lr;
        float bv = (gn < halfN) ? bl[gn] : br[gn - halfN];
        out[(size_t)gm * Nout + gn] = __float2bfloat16(acc[mt][nt][r2] + bv);
      }
    }
  }
}

// ---------------- fused prep: vectorized casts (short8 stores) + degree histogram ----------------
struct CastSeg { const float* src; __hip_bfloat16* dst; int rows, K, Kp, row0, start; };
struct CastArgs { CastSeg s[7]; int total; };  // start/total in 8-elem GROUPS

__global__ __launch_bounds__(256) void k_prep(CastArgs A, const int* __restrict__ ei,
                                              int E, int N, int* __restrict__ deg) {
  int stride = gridDim.x * blockDim.x;
  int tid0 = blockIdx.x * blockDim.x + threadIdx.x;
  for (int gidx = tid0; gidx < A.total; gidx += stride) {
    int si = 0;
#pragma unroll
    for (int j = 1; j < 7; j++) if (gidx >= A.s[j].start) si = j;
    CastSeg sg = A.s[si];
    int lg = gidx - sg.start;           // group within segment
    int gpr = sg.Kp >> 3;               // groups per row (Kp % 8 == 0 always)
    int r = lg / gpr, k0 = (lg - r * gpr) << 3;
    const float* srow = sg.src + (size_t)r * sg.K;
    short8 o;
#pragma unroll
    for (int j = 0; j < 8; ++j) {
      int k = k0 + j;
      float v = (k < sg.K) ? srow[k] : 0.f;
      __hip_bfloat16 b = __float2bfloat16(v);
      o[j] = __builtin_bit_cast(short, b);
    }
    *(short8*)(sg.dst + (size_t)(sg.row0 + r) * sg.Kp + k0) = o;
  }
  int ET = E + N;
  for (int e = tid0; e < ET; e += stride) {
    int d = (e < E) ? ei[E + e] : (e - E);
    atomicAdd(&deg[d], 1);
  }
}

// ---------------- scan + degree-bucket permutation (single block) ----------------
__global__ __launch_bounds__(256) void k_scan_perm(const int* __restrict__ deg, int N,
                                                   int* __restrict__ rp, int* __restrict__ cursor,
                                                   int* __restrict__ perm) {
  __shared__ int part[256];
  __shared__ int bcnt[64];
  __shared__ int boff[64];
  int t = threadIdx.x;
  int chunk = (N + 255) / 256;
  int lo = t * chunk;
  int hi = lo + chunk; if (hi > N) hi = N;
  int s = 0;
  for (int i = lo; i < hi; ++i) s += deg[i];
  part[t] = s;
  if (t < 64) bcnt[t] = 0;
  __syncthreads();
  for (int off = 1; off < 256; off <<= 1) {
    int x = (t >= off) ? part[t - off] : 0;
    __syncthreads();
    part[t] += x;
    __syncthreads();
  }
  int run = (t == 0) ? 0 : part[t - 1];
  for (int i = lo; i < hi; ++i) {
    rp[i] = run;
    cursor[i] = run;
    run += deg[i];
    int b = deg[i] < 63 ? deg[i] : 63;
    atomicAdd(&bcnt[b], 1);
  }
  if (t == 255) rp[N] = run;
  __syncthreads();
  if (t == 0) {
    int acc = 0;
    for (int b = 63; b >= 0; --b) { boff[b] = acc; acc += bcnt[b]; }  // descending degree
  }
  __syncthreads();
  for (int i = lo; i < hi; ++i) {
    int b = deg[i] < 63 ? deg[i] : 63;
    int pos = atomicAdd(&boff[b], 1);
    perm[pos] = i;
  }
}

// scatter + zero the srcs pad (unconditional prefetch reads land in valid memory)
__global__ void k_scatter(const int* __restrict__ ei, int E, int N,
                          int* __restrict__ cursor, int* __restrict__ srcs) {
  int e = blockIdx.x * blockDim.x + threadIdx.x;
  int ET = E + N;
  if (e >= ET) {
    if (e < ET + 64) srcs[e] = 0;
    return;
  }
  int s = (e < E) ? ei[e] : (e - E);
  int d = (e < E) ? ei[E + e] : (e - E);
  int pos = atomicAdd(&cursor[d], 1);
  srcs[pos] = s;
}

// ---------------- layers 1-2 edge phase: 2 edges/wave, 2-deep prefetch ----------------
__global__ __launch_bounds__(256) void k_edge2(
    const __hip_bfloat16* __restrict__ xl, const __hip_bfloat16* __restrict__ xr,
    const int* __restrict__ rp, const int* __restrict__ srcs,
    const int* __restrict__ perm, const float* __restrict__ att,
    const float* __restrict__ bias, int N, __hip_bfloat16* __restrict__ out) {
  const int LD = 1024;
  int lane = threadIdx.x & 63;
  int hl = lane & 31;
  bool hi = lane >= 32;
  int nw = (blockIdx.x * blockDim.x + threadIdx.x) >> 6;
  if (nw >= N) return;
  int n = __builtin_amdgcn_readfirstlane(perm[nw]);

  f32x2 a06[8], a04[8], xrv2[8];
#pragma unroll
  for (int p = 0; p < 8; ++p) {
    float alo = att[hl * 16 + 2 * p], ahi = att[hl * 16 + 2 * p + 1];
    a06[p].x = 0.6f * alo; a06[p].y = 0.6f * ahi;
    a04[p].x = 0.4f * alo; a04[p].y = 0.4f * ahi;
  }
  {
    const unsigned int* xw = (const unsigned int*)(xr + (size_t)n * LD + hl * 16);
#pragma unroll
    for (int p = 0; p < 8; ++p) xrv2[p] = unpk(xw[p]);
  }

  int s0 = __builtin_amdgcn_readfirstlane(rp[n]);
  int s1 = __builtin_amdgcn_readfirstlane(rp[n + 1]);
  int len = s1 - s0;
  int lenA = (len + 1) >> 1;
  int lenB = len - lenA;
  int iA = s0, iB = s0 + lenA;
  unsigned laneOff = (unsigned)(hl * 32);

  float sum = 0.f;
  f32x2 acc2[8];
#pragma unroll
  for (int p = 0; p < 8; ++p) { acc2[p].x = 0.f; acc2[p].y = 0.f; }

  auto loadPair = [&](int t, u32x4& lo, u32x4& hh) {
    unsigned offA = ((unsigned)srcs[iA + t]) << 11;   // *2048 B/row
    unsigned offB = ((unsigned)srcs[iB + t]) << 11;
    unsigned off = (hi ? offB : offA) + laneOff;
    const u32x4* p = (const u32x4*)((const char*)xl + off);
    lo = p[0]; hh = p[1];
  };

  u32x4 lo0, hi0, lo1, hi1, lo2, hi2;
  loadPair(0, lo0, hi0);
  loadPair(1, lo1, hi1);
  for (int t = 0; t < lenA; ++t) {
    loadPair(t + 2, lo2, hi2);
    f32x2 xv2[8], p2; p2.x = 0.f; p2.y = 0.f;
#pragma unroll
    for (int p = 0; p < 8; ++p) {
      unsigned int wv = (p < 4) ? lo0[p & 3] : hi0[p & 3];
      xv2[p] = unpk(wv);
      f32x2 s = pk_add(xv2[p], xrv2[p]);
      f32x2 sa = pk_abs(s);
      p2 = pk_fma(a06[p], s, p2);
      p2 = pk_fma(a04[p], sa, p2);
    }
    float pp = p2.x + p2.y;
    pp = dpp_add<0xB1>(pp);
    pp = dpp_add<0x4E>(pp);
    pp += __shfl_xor(pp, 4, 64);
    float wgt = __expf(pp);
    if (hi && t >= lenB) wgt = 0.f;
    sum += wgt;
    f32x2 w2; w2.x = wgt; w2.y = wgt;
#pragma unroll
    for (int p = 0; p < 8; ++p) acc2[p] = pk_fma(w2, xv2[p], acc2[p]);
    lo0 = lo1; hi0 = hi1; lo1 = lo2; hi1 = hi2;
  }

  sum += __shfl_xor(sum, 32, 64);
#pragma unroll
  for (int p = 0; p < 8; ++p) {
    f32x2 o;
    o.x = __shfl_xor(acc2[p].x, 32, 64);
    o.y = __shfl_xor(acc2[p].y, 32, 64);
    acc2[p] = pk_add(acc2[p], o);
  }
  float inv = 1.f / (sum + 1e-16f);
  int cbase = hl * 16 + (hi ? 8 : 0);
  short8 o;
#pragma unroll
  for (int q = 0; q < 4; ++q) {
    f32x2 v = hi ? acc2[4 + q] : acc2[q];
    float r0 = v.x * inv + bias[cbase + 2 * q];
    float r1 = v.y * inv + bias[cbase + 2 * q + 1];
    r0 = r0 > 0.f ? r0 : expm1f(r0);   // ELU
    r1 = r1 > 0.f ? r1 : expm1f(r1);
    __hip_bfloat16 b0 = __float2bfloat16(r0);
    __hip_bfloat16 b1 = __float2bfloat16(r1);
    o[2 * q] = __builtin_bit_cast(short, b0);
    o[2 * q + 1] = __builtin_bit_cast(short, b1);
  }
  *(short8*)(out + (size_t)n * 512 + cbase) = o;
}

// ---------------- layer 3 edge phase: 4 edges per wave ----------------
__global__ __launch_bounds__(256) void k_edge4(
    const __hip_bfloat16* __restrict__ xl, const __hip_bfloat16* __restrict__ xr,
    const int* __restrict__ rp, const int* __restrict__ srcs,
    const int* __restrict__ perm, const float* __restrict__ att,
    const float* __restrict__ bias, int N, float* __restrict__ out) {
  const int LD = 256;
  int lane = threadIdx.x & 63;
  int hl = lane & 15;
  int g = lane >> 4;
  int nw = (blockIdx.x * blockDim.x + threadIdx.x) >> 6;
  if (nw >= N) return;
  int n = __builtin_amdgcn_readfirstlane(perm[nw]);

  f32x2 a06[4], a04[4], xrv2[4];
#pragma unroll
  for (int p = 0; p < 4; ++p) {
    float alo = att[hl * 8 + 2 * p], ahi = att[hl * 8 + 2 * p + 1];
    a06[p].x = 0.6f * alo; a06[p].y = 0.6f * ahi;
    a04[p].x = 0.4f * alo; a04[p].y = 0.4f * ahi;
  }
  {
    const unsigned int* xw = (const unsigned int*)(xr + (size_t)n * LD + hl * 8);
#pragma unroll
    for (int p = 0; p < 4; ++p) xrv2[p] = unpk(xw[p]);
  }

  int s0 = __builtin_amdgcn_readfirstlane(rp[n]);
  int s1 = __builtin_amdgcn_readfirstlane(rp[n + 1]);
  int len = s1 - s0;
  int base = len >> 2, rem = len & 3;
  int l0 = base + (rem > 0 ? 1 : 0);
  int l1 = base + (rem > 1 ? 1 : 0);
  int l2 = base + (rem > 2 ? 1 : 0);
  int st0 = 0, st1 = l0, st2 = l0 + l1, st3 = l0 + l1 + l2;
  int lg = base + ((g < rem) ? 1 : 0);
  int itmax = (len < 4) ? 1 : l0;
  if (l0 == 0) itmax = 0;
  unsigned laneOff = (unsigned)(hl * 16);

  float sum = 0.f;
  f32x2 acc2[4];
#pragma unroll
  for (int p = 0; p < 4; ++p) { acc2[p].x = 0.f; acc2[p].y = 0.f; }

  auto loadRow = [&](int t) -> u32x4 {
    unsigned o0 = ((unsigned)srcs[s0 + st0 + t]) << 9;
    unsigned o1 = ((unsigned)srcs[s0 + st1 + t]) << 9;
    unsigned o2 = ((unsigned)srcs[s0 + st2 + t]) << 9;
    unsigned o3 = ((unsigned)srcs[s0 + st3 + t]) << 9;
    unsigned off = ((g == 0) ? o0 : (g == 1) ? o1 : (g == 2) ? o2 : o3) + laneOff;
    return *(const u32x4*)((const char*)xl + off);
  };

  u32x4 cur = loadRow(0);
  for (int t = 0; t < itmax; ++t) {
    u32x4 nxt = loadRow(t + 1);
    f32x2 xv2[4], p2; p2.x = 0.f; p2.y = 0.f;
#pragma unroll
    for (int p = 0; p < 4; ++p) {
      xv2[p] = unpk(cur[p]);
      f32x2 s = pk_add(xv2[p], xrv2[p]);
      f32x2 sa = pk_abs(s);
      p2 = pk_fma(a06[p], s, p2);
      p2 = pk_fma(a04[p], sa, p2);
    }
    float pp = p2.x + p2.y;
    pp = row16_sum(pp);
    float wgt = (t < lg) ? __expf(pp) : 0.f;
    sum += wgt;
    f32x2 w2; w2.x = wgt; w2.y = wgt;
#pragma unroll
    for (int p = 0; p < 4; ++p) acc2[p] = pk_fma(w2, xv2[p], acc2[p]);
    cur = nxt;
  }

  sum += __shfl_xor(sum, 16, 64);
  sum += __shfl_xor(sum, 32, 64);
#pragma unroll
  for (int p = 0; p < 4; ++p) {
    acc2[p].x += __shfl_xor(acc2[p].x, 16, 64);
    acc2[p].y += __shfl_xor(acc2[p].y, 16, 64);
    acc2[p].x += __shfl_xor(acc2[p].x, 32, 64);
    acc2[p].y += __shfl_xor(acc2[p].y, 32, 64);
  }
  float inv = 1.f / (sum + 1e-16f);
  f32x2 v = (g == 0) ? acc2[0] : (g == 1) ? acc2[1] : (g == 2) ? acc2[2] : acc2[3];
  int cb = hl * 8 + 2 * g;
  f32x2 r;
  r.x = v.x * inv + bias[cb];
  r.y = v.y * inv + bias[cb + 1];
  *(f32x2*)(out + (size_t)n * 128 + cb) = r;
}

extern "C" void kernel_launch(void* const* d_in, const int* in_sizes, int n_in,
                              void* d_out, int out_size, void* d_ws, size_t ws_size,
                              hipStream_t stream) {
  const int IN = 77, Kp1 = 96, Hh = 4, Cc = 128, HC = Hh * Cc;  // 512
  const int N = in_sizes[0] / IN;
  const int E = in_sizes[1] / 2;
  const int ET = E + N;

  const float* x   = (const float*)d_in[0];
  const int*   ei  = (const int*)d_in[1];
  const float* Wl1 = (const float*)d_in[2];  const float* bl1 = (const float*)d_in[3];
  const float* Wr1 = (const float*)d_in[4];  const float* br1 = (const float*)d_in[5];
  const float* att1= (const float*)d_in[6];  const float* b1  = (const float*)d_in[7];
  const float* Wl2 = (const float*)d_in[8];  const float* bl2 = (const float*)d_in[9];
  const float* Wr2 = (const float*)d_in[10]; const float* br2 = (const float*)d_in[11];
  const float* att2= (const float*)d_in[12]; const float* b2  = (const float*)d_in[13];
  const float* Wl3 = (const float*)d_in[14]; const float* bl3 = (const float*)d_in[15];
  const float* Wr3 = (const float*)d_in[16]; const float* br3 = (const float*)d_in[17];
  const float* att3= (const float*)d_in[18]; const float* b3  = (const float*)d_in[19];
  float* out = (float*)d_out;

  char* w = (char*)d_ws;
  size_t off = 0;
  auto alloc = [&](size_t bytes) -> void* {
    void* p = w + off;
    off += (bytes + 255) & ~(size_t)255;
    return p;
  };
  __hip_bfloat16* xlr = (__hip_bfloat16*)alloc((size_t)N * 2 * HC * 2);
  __hip_bfloat16* hb  = (__hip_bfloat16*)alloc((size_t)N * HC * 2);
  __hip_bfloat16* Wc1 = (__hip_bfloat16*)alloc((size_t)2 * HC * Kp1 * 2);
  __hip_bfloat16* Wc2 = (__hip_bfloat16*)alloc((size_t)2 * HC * HC * 2);
  __hip_bfloat16* Wc3 = (__hip_bfloat16*)alloc((size_t)2 * Cc * HC * 2);
  int*   deg    = (int*)alloc((size_t)N * 4);
  int*   rp     = (int*)alloc((size_t)(N + 1) * 4);
  int*   cursor = (int*)alloc((size_t)N * 4);
  int*   srcs   = (int*)alloc((size_t)(ET + 64) * 4);
  int*   perm   = (int*)alloc((size_t)N * 4);

  // ---- fused prep: vectorized casts (group = 8 elems) + degree histogram ----
  CastArgs CA;
  int cum = 0;
  auto seg = [&](int idx, const float* src, __hip_bfloat16* dst, int rows, int K, int Kp, int row0) {
    CA.s[idx] = {src, dst, rows, K, Kp, row0, cum};
    cum += rows * (Kp >> 3);   // groups
  };
  seg(0, Wl1, Wc1, HC, IN, Kp1, 0);
  seg(1, Wr1, Wc1, HC, IN, Kp1, HC);
  seg(2, Wl2, Wc2, HC, HC, HC, 0);
  seg(3, Wr2, Wc2, HC, HC, HC, HC);
  seg(4, Wl3, Wc3, Cc, HC, HC, 0);
  seg(5, Wr3, Wc3, Cc, HC, HC, Cc);
  seg(6, x,   hb,  N,  IN, Kp1, 0);
  CA.total = cum;

  hipMemsetAsync(deg, 0, (size_t)N * 4, stream);
  k_prep<<<1024, 256, 0, stream>>>(CA, ei, E, N, deg);
  k_scan_perm<<<1, 256, 0, stream>>>(deg, N, rp, cursor, perm);
  k_scatter<<<(ET + 64 + 255) / 256, 256, 0, stream>>>(ei, E, N, cursor, srcs);

  int nodeBlocks = (N + 3) / 4;
  int mb = (N + 127) / 128;

  // ---- layer 1 ----
  {
    dim3 g(2 * HC / 128, mb);
    gemm_mfma<<<g, 256, 0, stream>>>(hb, Wc1, bl1, br1, HC, xlr, N, Kp1, 2 * HC);
    k_edge2<<<nodeBlocks, 256, 0, stream>>>(xlr, xlr + HC, rp, srcs, perm, att1, b1, N, hb);
  }
  // ---- layer 2 ----
  {
    dim3 g(2 * HC / 128, mb);
    gemm_mfma<<<g, 256, 0, stream>>>(hb, Wc2, bl2, br2, HC, xlr, N, HC, 2 * HC);
    k_edge2<<<nodeBlocks, 256, 0, stream>>>(xlr, xlr + HC, rp, srcs, perm, att2, b2, N, hb);
  }
  // ---- layer 3 (1 head, 128 ch, fp32 out, no ELU) ----
  {
    dim3 g(2 * Cc / 128, mb);
    gemm_mfma<<<g, 256, 0, stream>>>(hb, Wc3, bl3, br3, Cc, xlr, N, HC, 2 * Cc);
    k_edge4<<<nodeBlocks, 256, 0, stream>>>(xlr, xlr + Cc, rp, srcs, perm, att3, b3, N, out);
  }
}